// Round 1
// baseline (188.088 us; speedup 1.0000x reference)
//
#include <hip/hip_runtime.h>
#include <hip/hip_bf16.h>

// Problem constants: N=100000 up nodes, F=64 features, M=100000 down nodes,
// K=32 neighbors per down node.
#define F_DIM 64
#define K_NB  32
#define CAP   16   // bucket capacity; P(Poisson(1) >= 16)*1e5 ~ 2e-9 total

typedef float        f32x4 __attribute__((ext_vector_type(4)));
typedef int          i32x4 __attribute__((ext_vector_type(4)));
typedef unsigned int u32;

// bf16 helpers: table is stored as bf16, accumulation stays fp32.
__device__ inline u32 f2b(float f) {            // fp32 -> bf16 bits (RNE)
    u32 u = __float_as_uint(f);
    u32 r = ((u >> 16) & 1u) + 0x7fffu;
    return (u + r) >> 16;
}
__device__ inline float blo(u32 u) { return __uint_as_float(u << 16); }
__device__ inline float bhi(u32 u) { return __uint_as_float(u & 0xffff0000u); }

// ---------------------------------------------------------------------------
// Step A: bucket[m][slot] = i for each up node i with sel[i]==m.
// ---------------------------------------------------------------------------
__global__ __launch_bounds__(256) void bucket_fill_kernel(
    const int* __restrict__ sel_idx,   // [N]
    int*       __restrict__ cnt,       // [M], pre-zeroed
    int*       __restrict__ bucket,    // [M, CAP]
    int N)
{
    int i = blockIdx.x * blockDim.x + threadIdx.x;
    if (i >= N) return;
    int m = sel_idx[i];
    int slot = atomicAdd(&cnt[m], 1);
    if (slot < CAP) bucket[m * CAP + slot] = i;
}

// ---------------------------------------------------------------------------
// Step B: down_h[m] (bf16) = sum of feature rows in bucket[m].
// Quarter-wave (16 lanes) per node; lane q owns features 4q..4q+3.
// First 4 bucket entries branch-free; c>4 tail is rare (P ~ 0.4%).
// Features are streamed once -> nontemporal loads (don't evict live L2 data).
// ---------------------------------------------------------------------------
__global__ __launch_bounds__(256) void build_down_f_bf16_kernel(
    const f32x4* __restrict__ features4,  // [N, 16]
    const int*   __restrict__ cnt,        // [M]
    const i32x4* __restrict__ bucket4,    // [M, CAP/4]
    unsigned short* __restrict__ down_h,  // [M, 64] bf16
    int M)
{
    int t = blockIdx.x * blockDim.x + threadIdx.x;
    int m = t >> 4;
    int q = t & 15;
    if (m >= M) return;
    int c = cnt[m]; c = c < CAP ? c : CAP;
    i32x4 b4 = bucket4[(size_t)m * (CAP / 4)];   // first 4 slots in one 16B load

    int i0 = (0 < c) ? b4.x : 0;  float g0 = (0 < c) ? 1.f : 0.f;
    int i1 = (1 < c) ? b4.y : 0;  float g1 = (1 < c) ? 1.f : 0.f;
    int i2 = (2 < c) ? b4.z : 0;  float g2 = (2 < c) ? 1.f : 0.f;
    int i3 = (3 < c) ? b4.w : 0;  float g3 = (3 < c) ? 1.f : 0.f;

    f32x4 v0 = __builtin_nontemporal_load(&features4[(size_t)i0 * 16 + q]);
    f32x4 v1 = __builtin_nontemporal_load(&features4[(size_t)i1 * 16 + q]);
    f32x4 v2 = __builtin_nontemporal_load(&features4[(size_t)i2 * 16 + q]);
    f32x4 v3 = __builtin_nontemporal_load(&features4[(size_t)i3 * 16 + q]);

    f32x4 acc;
    acc.x = g0 * v0.x + g1 * v1.x + g2 * v2.x + g3 * v3.x;
    acc.y = g0 * v0.y + g1 * v1.y + g2 * v2.y + g3 * v3.y;
    acc.z = g0 * v0.z + g1 * v1.z + g2 * v2.z + g3 * v3.z;
    acc.w = g0 * v0.w + g1 * v1.w + g2 * v2.w + g3 * v3.w;

    if (c > 4) {
        const int* bk = (const int*)(bucket4 + (size_t)m * (CAP / 4));
        for (int j = 4; j < c; ++j) {
            int i = bk[j];
            f32x4 v = __builtin_nontemporal_load(&features4[(size_t)i * 16 + q]);
            acc.x += v.x; acc.y += v.y; acc.z += v.z; acc.w += v.w;
        }
    }
    uint2 o;
    o.x = f2b(acc.x) | (f2b(acc.y) << 16);
    o.y = f2b(acc.z) | (f2b(acc.w) << 16);
    *(uint2*)(down_h + (size_t)m * F_DIM + q * 4) = o;
}

// ---------------------------------------------------------------------------
// Phase 2 (bf16 table): out[m] = (1/K) * sum_k w[m,k] * down_h[nidx[m,k]]
// EIGHTH-wave (8 lanes) per node; lane q owns features 8q..8q+7, so each
// gather is a 16B uint4 (8 bf16) and a node row is one contiguous 128B
// segment.
// vs R0-baseline: 16 gathers in flight per thread (was 8) -> 2x in-flight
// bytes per wave. Kernel is latency-bound (47% HBM, 22% VALU, FETCH near the
// per-XCD compulsory floor), so concurrency is the lever, not locality.
// nidx/weights/out are pure streams -> nontemporal, so they stop evicting
// table lines from L2. __launch_bounds__(256,4) caps VGPR at 128
// (16 uint4 g-regs = 64 + 16 w + 8 acc + addr ~= 115).
// ---------------------------------------------------------------------------
__global__ __launch_bounds__(256, 4) void gather_mean_bf16_kernel(
    const unsigned short* __restrict__ down_h,   // [M, 64] bf16
    const f32x4*          __restrict__ weights4, // [M, 8]
    const i32x4*          __restrict__ nidx4,    // [M, 8]
    f32x4*                __restrict__ out4,     // [M, 16] fp32
    int M)
{
    int t = blockIdx.x * blockDim.x + threadIdx.x;
    int m = t >> 3;
    int q = t & 7;       // feature octet: features 8q..8q+7
    if (m >= M) return;

    const i32x4* ni = nidx4    + (size_t)m * (K_NB / 4);
    const f32x4* wp = weights4 + (size_t)m * (K_NB / 4);
    // 32-bit byte offsets into the 12.8MB table: j*128u fits easily.
    const unsigned char* bp = (const unsigned char*)down_h + (unsigned)q * 16u;

    float a0 = 0.f, a1 = 0.f, a2 = 0.f, a3 = 0.f;
    float a4 = 0.f, a5 = 0.f, a6 = 0.f, a7 = 0.f;

#define SEL(jv, wv, Ic, Wc) unsigned jv = (Ic) < 0 ? 0u : (unsigned)(Ic); \
                            float    wv = (Ic) < 0 ? 0.f : (Wc);
#define GAT(gv, jv) uint4 gv = *(const uint4*)(bp + (size_t)((jv) * 128u));
#define ACC(gv, wv) \
    a0 += wv * blo(gv.x); a1 += wv * bhi(gv.x); \
    a2 += wv * blo(gv.y); a3 += wv * bhi(gv.y); \
    a4 += wv * blo(gv.z); a5 += wv * bhi(gv.z); \
    a6 += wv * blo(gv.w); a7 += wv * bhi(gv.w);

    #pragma unroll
    for (int gb = 0; gb < 2; ++gb) {
        // 16 neighbors per group: indices/weights streamed nontemporally.
        i32x4 I0 = __builtin_nontemporal_load(ni + 4 * gb + 0);
        i32x4 I1 = __builtin_nontemporal_load(ni + 4 * gb + 1);
        i32x4 I2 = __builtin_nontemporal_load(ni + 4 * gb + 2);
        i32x4 I3 = __builtin_nontemporal_load(ni + 4 * gb + 3);
        f32x4 W0 = __builtin_nontemporal_load(wp + 4 * gb + 0);
        f32x4 W1 = __builtin_nontemporal_load(wp + 4 * gb + 1);
        f32x4 W2 = __builtin_nontemporal_load(wp + 4 * gb + 2);
        f32x4 W3 = __builtin_nontemporal_load(wp + 4 * gb + 3);

        SEL(j0,  w0,  I0.x, W0.x)  SEL(j1,  w1,  I0.y, W0.y)
        SEL(j2,  w2,  I0.z, W0.z)  SEL(j3,  w3,  I0.w, W0.w)
        SEL(j4,  w4,  I1.x, W1.x)  SEL(j5,  w5,  I1.y, W1.y)
        SEL(j6,  w6,  I1.z, W1.z)  SEL(j7,  w7,  I1.w, W1.w)
        SEL(j8,  w8,  I2.x, W2.x)  SEL(j9,  w9,  I2.y, W2.y)
        SEL(j10, w10, I2.z, W2.z)  SEL(j11, w11, I2.w, W2.w)
        SEL(j12, w12, I3.x, W3.x)  SEL(j13, w13, I3.y, W3.y)
        SEL(j14, w14, I3.z, W3.z)  SEL(j15, w15, I3.w, W3.w)

        // All 16 gathers issued before any consume -> 16 lines in flight.
        GAT(g0,  j0)   GAT(g1,  j1)   GAT(g2,  j2)   GAT(g3,  j3)
        GAT(g4,  j4)   GAT(g5,  j5)   GAT(g6,  j6)   GAT(g7,  j7)
        GAT(g8,  j8)   GAT(g9,  j9)   GAT(g10, j10)  GAT(g11, j11)
        GAT(g12, j12)  GAT(g13, j13)  GAT(g14, j14)  GAT(g15, j15)

        ACC(g0,  w0)   ACC(g1,  w1)   ACC(g2,  w2)   ACC(g3,  w3)
        ACC(g4,  w4)   ACC(g5,  w5)   ACC(g6,  w6)   ACC(g7,  w7)
        ACC(g8,  w8)   ACC(g9,  w9)   ACC(g10, w10)  ACC(g11, w11)
        ACC(g12, w12)  ACC(g13, w13)  ACC(g14, w14)  ACC(g15, w15)
    }
#undef SEL
#undef GAT
#undef ACC

    const float s = 1.0f / (float)K_NB;
    size_t o = (size_t)m * 16 + q * 2;
    f32x4 r0; r0.x = a0 * s; r0.y = a1 * s; r0.z = a2 * s; r0.w = a3 * s;
    f32x4 r1; r1.x = a4 * s; r1.y = a5 * s; r1.z = a6 * s; r1.w = a7 * s;
    __builtin_nontemporal_store(r0, &out4[o + 0]);
    __builtin_nontemporal_store(r1, &out4[o + 1]);
}

// ---------------------------------------------------------------------------
// Fallback path (ws too small for buckets): fp32 memset + atomic scatter +
// fp32 gather.
// ---------------------------------------------------------------------------
__global__ __launch_bounds__(256) void scatter_add_kernel(
    const float* __restrict__ features, const int* __restrict__ sel_idx,
    float* __restrict__ down_f, int N)
{
    int t = blockIdx.x * blockDim.x + threadIdx.x;
    int i  = t >> 5;
    int fp = (t & 31);
    if (i >= N) return;
    int dst = sel_idx[i];
    float2 v = ((const float2*)features)[(size_t)i * (F_DIM / 2) + fp];
    float* d = down_f + (size_t)dst * F_DIM + fp * 2;
    atomicAdd(d + 0, v.x);
    atomicAdd(d + 1, v.y);
}

__global__ __launch_bounds__(256) void gather_mean_f32_kernel(
    const float2* __restrict__ down_f2, const float* __restrict__ weights,
    const int* __restrict__ nidx, float2* __restrict__ out2, int M)
{
    int t  = blockIdx.x * blockDim.x + threadIdx.x;
    int m  = t >> 5;
    int fp = t & 31;
    if (m >= M) return;
    const i32x4* ni4 = (const i32x4*)(nidx    + (size_t)m * K_NB);
    const f32x4* wp4 = (const f32x4*)(weights + (size_t)m * K_NB);
    float accx = 0.f, accy = 0.f;
    #pragma unroll
    for (int q = 0; q < K_NB / 4; ++q) {
        i32x4 iv = ni4[q];
        f32x4 wv = wp4[q];
        int i0 = iv.x < 0 ? 0 : iv.x;  float w0 = iv.x < 0 ? 0.f : wv.x;
        int i1 = iv.y < 0 ? 0 : iv.y;  float w1 = iv.y < 0 ? 0.f : wv.y;
        int i2 = iv.z < 0 ? 0 : iv.z;  float w2 = iv.z < 0 ? 0.f : wv.z;
        int i3 = iv.w < 0 ? 0 : iv.w;  float w3 = iv.w < 0 ? 0.f : wv.w;
        float2 v0 = down_f2[(size_t)i0 * (F_DIM / 2) + fp];
        float2 v1 = down_f2[(size_t)i1 * (F_DIM / 2) + fp];
        float2 v2 = down_f2[(size_t)i2 * (F_DIM / 2) + fp];
        float2 v3 = down_f2[(size_t)i3 * (F_DIM / 2) + fp];
        accx += w0 * v0.x; accy += w0 * v0.y;
        accx += w1 * v1.x; accy += w1 * v1.y;
        accx += w2 * v2.x; accy += w2 * v2.y;
        accx += w3 * v3.x; accy += w3 * v3.y;
    }
    float2 r;
    r.x = accx * (1.0f / (float)K_NB);
    r.y = accy * (1.0f / (float)K_NB);
    out2[(size_t)m * (F_DIM / 2) + fp] = r;
}

extern "C" void kernel_launch(void* const* d_in, const int* in_sizes, int n_in,
                              void* d_out, int out_size, void* d_ws, size_t ws_size,
                              hipStream_t stream) {
    const float* features = (const float*)d_in[0];  // [N,64]
    const float* weights  = (const float*)d_in[1];  // [M,32,1]
    const int*   sel_idx  = (const int*)  d_in[2];  // [N,1]
    const int*   nidx     = (const int*)  d_in[3];  // [M,32]
    float*       out      = (float*)d_out;          // [M,64]

    const int N = in_sizes[2];            // 100000
    const int M = in_sizes[3] / K_NB;     // 100000

    size_t downh_bytes  = (size_t)M * F_DIM * sizeof(unsigned short); // 12.8 MB
    size_t cnt_bytes    = (size_t)M * sizeof(int);                    //  0.4 MB
    size_t bucket_bytes = (size_t)M * CAP * sizeof(int);              //  6.4 MB

    if (ws_size >= downh_bytes + cnt_bytes + bucket_bytes) {
        // Fast path: inverted-index build into a bf16 table, bf16 gather.
        unsigned short* down_h = (unsigned short*)d_ws;
        int* cnt    = (int*)((char*)d_ws + downh_bytes);
        int* bucket = cnt + M;

        hipMemsetAsync(cnt, 0, cnt_bytes, stream);
        bucket_fill_kernel<<<(N + 255) / 256, 256, 0, stream>>>(
            sel_idx, cnt, bucket, N);
        build_down_f_bf16_kernel<<<(M * 16 + 255) / 256, 256, 0, stream>>>(
            (const f32x4*)features, cnt, (const i32x4*)bucket, down_h, M);
        gather_mean_bf16_kernel<<<(M * 8 + 255) / 256, 256, 0, stream>>>(
            down_h, (const f32x4*)weights, (const i32x4*)nidx,
            (f32x4*)out, M);
    } else {
        // Fallback: fp32 table, atomic scatter, fp32 gather.
        float* down_f = (float*)d_ws;     // [M,64] = 25.6 MB
        hipMemsetAsync(down_f, 0, (size_t)M * F_DIM * sizeof(float), stream);
        scatter_add_kernel<<<(N * 32 + 255) / 256, 256, 0, stream>>>(
            features, sel_idx, down_f, N);
        gather_mean_f32_kernel<<<(M * 32 + 255) / 256, 256, 0, stream>>>(
            (const float2*)down_f, weights, nidx, (float2*)out, M);
    }
}

// Round 2
// 161.405 us; speedup vs baseline: 1.1653x; 1.1653x over previous
//
#include <hip/hip_runtime.h>
#include <hip/hip_bf16.h>

// Problem constants: N=100000 up nodes, F=64 features, M=100000 down nodes,
// K=32 neighbors per down node.
#define F_DIM 64
#define K_NB  32
#define CAP   16   // bucket capacity; P(Poisson(1) >= 16)*1e5 ~ 2e-9 total

typedef float        f32x4 __attribute__((ext_vector_type(4)));
typedef int          i32x4 __attribute__((ext_vector_type(4)));
typedef unsigned int u32;

// bf16 helpers: table is stored as bf16, accumulation stays fp32.
__device__ inline u32 f2b(float f) {            // fp32 -> bf16 bits (RNE)
    u32 u = __float_as_uint(f);
    u32 r = ((u >> 16) & 1u) + 0x7fffu;
    return (u + r) >> 16;
}
__device__ inline float blo(u32 u) { return __uint_as_float(u << 16); }
__device__ inline float bhi(u32 u) { return __uint_as_float(u & 0xffff0000u); }

// ---------------------------------------------------------------------------
// Step A: bucket[m][slot] = i for each up node i with sel[i]==m.
// ---------------------------------------------------------------------------
__global__ __launch_bounds__(256) void bucket_fill_kernel(
    const int* __restrict__ sel_idx,   // [N]
    int*       __restrict__ cnt,       // [M], pre-zeroed
    int*       __restrict__ bucket,    // [M, CAP]
    int N)
{
    int i = blockIdx.x * blockDim.x + threadIdx.x;
    if (i >= N) return;
    int m = sel_idx[i];
    int slot = atomicAdd(&cnt[m], 1);
    if (slot < CAP) bucket[m * CAP + slot] = i;
}

// ---------------------------------------------------------------------------
// Step B: down_h[m] (bf16) = sum of feature rows in bucket[m].
// Quarter-wave (16 lanes) per node; lane q owns features 4q..4q+3.
// First 4 bucket entries branch-free; c>4 tail is rare (P ~ 0.4%).
// Features are streamed once -> nontemporal loads (don't evict live L2 data).
// ---------------------------------------------------------------------------
__global__ __launch_bounds__(256) void build_down_f_bf16_kernel(
    const f32x4* __restrict__ features4,  // [N, 16]
    const int*   __restrict__ cnt,        // [M]
    const i32x4* __restrict__ bucket4,    // [M, CAP/4]
    unsigned short* __restrict__ down_h,  // [M, 64] bf16
    int M)
{
    int t = blockIdx.x * blockDim.x + threadIdx.x;
    int m = t >> 4;
    int q = t & 15;
    if (m >= M) return;
    int c = cnt[m]; c = c < CAP ? c : CAP;
    i32x4 b4 = bucket4[(size_t)m * (CAP / 4)];   // first 4 slots in one 16B load

    int i0 = (0 < c) ? b4.x : 0;  float g0 = (0 < c) ? 1.f : 0.f;
    int i1 = (1 < c) ? b4.y : 0;  float g1 = (1 < c) ? 1.f : 0.f;
    int i2 = (2 < c) ? b4.z : 0;  float g2 = (2 < c) ? 1.f : 0.f;
    int i3 = (3 < c) ? b4.w : 0;  float g3 = (3 < c) ? 1.f : 0.f;

    f32x4 v0 = __builtin_nontemporal_load(&features4[(size_t)i0 * 16 + q]);
    f32x4 v1 = __builtin_nontemporal_load(&features4[(size_t)i1 * 16 + q]);
    f32x4 v2 = __builtin_nontemporal_load(&features4[(size_t)i2 * 16 + q]);
    f32x4 v3 = __builtin_nontemporal_load(&features4[(size_t)i3 * 16 + q]);

    f32x4 acc;
    acc.x = g0 * v0.x + g1 * v1.x + g2 * v2.x + g3 * v3.x;
    acc.y = g0 * v0.y + g1 * v1.y + g2 * v2.y + g3 * v3.y;
    acc.z = g0 * v0.z + g1 * v1.z + g2 * v2.z + g3 * v3.z;
    acc.w = g0 * v0.w + g1 * v1.w + g2 * v2.w + g3 * v3.w;

    if (c > 4) {
        const int* bk = (const int*)(bucket4 + (size_t)m * (CAP / 4));
        for (int j = 4; j < c; ++j) {
            int i = bk[j];
            f32x4 v = __builtin_nontemporal_load(&features4[(size_t)i * 16 + q]);
            acc.x += v.x; acc.y += v.y; acc.z += v.z; acc.w += v.w;
        }
    }
    uint2 o;
    o.x = f2b(acc.x) | (f2b(acc.y) << 16);
    o.y = f2b(acc.z) | (f2b(acc.w) << 16);
    *(uint2*)(down_h + (size_t)m * F_DIM + q * 4) = o;
}

// ---------------------------------------------------------------------------
// Phase 2 (bf16 table): out[m] = (1/K) * sum_k w[m,k] * down_h[nidx[m,k]]
// EIGHTH-wave (8 lanes) per node; lane q owns features 8q..8q+7, so each
// gather is a 16B uint4 (8 bf16) and a node row is one contiguous 128B
// segment.
//
// R1 post-mortem: a flat 16-wide batch under __launch_bounds__(256,4) made
// the allocator pick VGPR=64 + scratch spills (WRITE_SIZE 25->61MB, dur
// 51.5->79us). R2: back to 8-wide batches, but software-pipelined 2-deep
// with NAMED buffers (A..D) so peak liveness is ~2 batches (~110 VGPR) and
// the vmcnt waits become counted (8 outstanding during each ACC) instead of
// drain-to-0. sched_barrier(0) between phases stops the compiler from
// hoisting a 3rd batch (register blowup) or sinking the prefetch.
// Streams (nidx/weights/out) stay nontemporal so they don't evict table
// lines from L2 (FETCH floor: 8 XCD x 12.8MB table + 51MB streams).
// ---------------------------------------------------------------------------
__global__ __launch_bounds__(256) void gather_mean_bf16_kernel(
    const unsigned short* __restrict__ down_h,   // [M, 64] bf16
    const f32x4*          __restrict__ weights4, // [M, 8]
    const i32x4*          __restrict__ nidx4,    // [M, 8]
    f32x4*                __restrict__ out4,     // [M, 16] fp32
    int M)
{
    int t = blockIdx.x * blockDim.x + threadIdx.x;
    int m = t >> 3;
    int q = t & 7;       // feature octet: features 8q..8q+7
    if (m >= M) return;

    const i32x4* ni = nidx4    + (size_t)m * (K_NB / 4);
    const f32x4* wp = weights4 + (size_t)m * (K_NB / 4);
    // 32-bit byte offsets into the 12.8MB table: j*128u fits easily.
    const unsigned char* bp = (const unsigned char*)down_h + (unsigned)q * 16u;

    float a0 = 0.f, a1 = 0.f, a2 = 0.f, a3 = 0.f;
    float a4 = 0.f, a5 = 0.f, a6 = 0.f, a7 = 0.f;

// Load indices+weights for batch b (8 neighbors) into suffix-s named regs.
#define LOADIW(s, b) \
    i32x4 Ix##s = __builtin_nontemporal_load(ni + 2 * (b));     \
    i32x4 Iy##s = __builtin_nontemporal_load(ni + 2 * (b) + 1); \
    f32x4 Wx##s = __builtin_nontemporal_load(wp + 2 * (b));     \
    f32x4 Wy##s = __builtin_nontemporal_load(wp + 2 * (b) + 1); \
    unsigned j0##s = Ix##s.x < 0 ? 0u : (unsigned)Ix##s.x;  float w0##s = Ix##s.x < 0 ? 0.f : Wx##s.x; \
    unsigned j1##s = Ix##s.y < 0 ? 0u : (unsigned)Ix##s.y;  float w1##s = Ix##s.y < 0 ? 0.f : Wx##s.y; \
    unsigned j2##s = Ix##s.z < 0 ? 0u : (unsigned)Ix##s.z;  float w2##s = Ix##s.z < 0 ? 0.f : Wx##s.z; \
    unsigned j3##s = Ix##s.w < 0 ? 0u : (unsigned)Ix##s.w;  float w3##s = Ix##s.w < 0 ? 0.f : Wx##s.w; \
    unsigned j4##s = Iy##s.x < 0 ? 0u : (unsigned)Iy##s.x;  float w4##s = Iy##s.x < 0 ? 0.f : Wy##s.x; \
    unsigned j5##s = Iy##s.y < 0 ? 0u : (unsigned)Iy##s.y;  float w5##s = Iy##s.y < 0 ? 0.f : Wy##s.y; \
    unsigned j6##s = Iy##s.z < 0 ? 0u : (unsigned)Iy##s.z;  float w6##s = Iy##s.z < 0 ? 0.f : Wy##s.z; \
    unsigned j7##s = Iy##s.w < 0 ? 0u : (unsigned)Iy##s.w;  float w7##s = Iy##s.w < 0 ? 0.f : Wy##s.w;

// Issue the 8 gathers for batch s (all independent, go into the vmcnt queue).
#define ISSUE(s) \
    uint4 g0##s = *(const uint4*)(bp + (size_t)(j0##s * 128u)); \
    uint4 g1##s = *(const uint4*)(bp + (size_t)(j1##s * 128u)); \
    uint4 g2##s = *(const uint4*)(bp + (size_t)(j2##s * 128u)); \
    uint4 g3##s = *(const uint4*)(bp + (size_t)(j3##s * 128u)); \
    uint4 g4##s = *(const uint4*)(bp + (size_t)(j4##s * 128u)); \
    uint4 g5##s = *(const uint4*)(bp + (size_t)(j5##s * 128u)); \
    uint4 g6##s = *(const uint4*)(bp + (size_t)(j6##s * 128u)); \
    uint4 g7##s = *(const uint4*)(bp + (size_t)(j7##s * 128u));

#define ACC1(gv, wv) \
    a0 += wv * blo(gv.x); a1 += wv * bhi(gv.x); \
    a2 += wv * blo(gv.y); a3 += wv * bhi(gv.y); \
    a4 += wv * blo(gv.z); a5 += wv * bhi(gv.z); \
    a6 += wv * blo(gv.w); a7 += wv * bhi(gv.w);

#define ACCB(s) \
    ACC1(g0##s, w0##s) ACC1(g1##s, w1##s) ACC1(g2##s, w2##s) ACC1(g3##s, w3##s) \
    ACC1(g4##s, w4##s) ACC1(g5##s, w5##s) ACC1(g6##s, w6##s) ACC1(g7##s, w7##s)

    // Prologue: batches A and B in flight (16 loads).
    LOADIW(A, 0) ISSUE(A)
    LOADIW(B, 1) ISSUE(B)
    // Phase 1: consume A (waits vmcnt<=8, B stays in flight).
    ACCB(A)
    __builtin_amdgcn_sched_barrier(0);
    // Phase 2: issue C, consume B (C in flight during ACC).
    LOADIW(C, 2) ISSUE(C)
    ACCB(B)
    __builtin_amdgcn_sched_barrier(0);
    // Phase 3: issue D, consume C.
    LOADIW(D, 3) ISSUE(D)
    ACCB(C)
    __builtin_amdgcn_sched_barrier(0);
    // Epilogue: consume D.
    ACCB(D)

#undef LOADIW
#undef ISSUE
#undef ACC1
#undef ACCB

    const float s = 1.0f / (float)K_NB;
    size_t o = (size_t)m * 16 + q * 2;
    f32x4 r0; r0.x = a0 * s; r0.y = a1 * s; r0.z = a2 * s; r0.w = a3 * s;
    f32x4 r1; r1.x = a4 * s; r1.y = a5 * s; r1.z = a6 * s; r1.w = a7 * s;
    __builtin_nontemporal_store(r0, &out4[o + 0]);
    __builtin_nontemporal_store(r1, &out4[o + 1]);
}

// ---------------------------------------------------------------------------
// Fallback path (ws too small for buckets): fp32 memset + atomic scatter +
// fp32 gather.
// ---------------------------------------------------------------------------
__global__ __launch_bounds__(256) void scatter_add_kernel(
    const float* __restrict__ features, const int* __restrict__ sel_idx,
    float* __restrict__ down_f, int N)
{
    int t = blockIdx.x * blockDim.x + threadIdx.x;
    int i  = t >> 5;
    int fp = (t & 31);
    if (i >= N) return;
    int dst = sel_idx[i];
    float2 v = ((const float2*)features)[(size_t)i * (F_DIM / 2) + fp];
    float* d = down_f + (size_t)dst * F_DIM + fp * 2;
    atomicAdd(d + 0, v.x);
    atomicAdd(d + 1, v.y);
}

__global__ __launch_bounds__(256) void gather_mean_f32_kernel(
    const float2* __restrict__ down_f2, const float* __restrict__ weights,
    const int* __restrict__ nidx, float2* __restrict__ out2, int M)
{
    int t  = blockIdx.x * blockDim.x + threadIdx.x;
    int m  = t >> 5;
    int fp = t & 31;
    if (m >= M) return;
    const i32x4* ni4 = (const i32x4*)(nidx    + (size_t)m * K_NB);
    const f32x4* wp4 = (const f32x4*)(weights + (size_t)m * K_NB);
    float accx = 0.f, accy = 0.f;
    #pragma unroll
    for (int q = 0; q < K_NB / 4; ++q) {
        i32x4 iv = ni4[q];
        f32x4 wv = wp4[q];
        int i0 = iv.x < 0 ? 0 : iv.x;  float w0 = iv.x < 0 ? 0.f : wv.x;
        int i1 = iv.y < 0 ? 0 : iv.y;  float w1 = iv.y < 0 ? 0.f : wv.y;
        int i2 = iv.z < 0 ? 0 : iv.z;  float w2 = iv.z < 0 ? 0.f : wv.z;
        int i3 = iv.w < 0 ? 0 : iv.w;  float w3 = iv.w < 0 ? 0.f : wv.w;
        float2 v0 = down_f2[(size_t)i0 * (F_DIM / 2) + fp];
        float2 v1 = down_f2[(size_t)i1 * (F_DIM / 2) + fp];
        float2 v2 = down_f2[(size_t)i2 * (F_DIM / 2) + fp];
        float2 v3 = down_f2[(size_t)i3 * (F_DIM / 2) + fp];
        accx += w0 * v0.x; accy += w0 * v0.y;
        accx += w1 * v1.x; accy += w1 * v1.y;
        accx += w2 * v2.x; accy += w2 * v2.y;
        accx += w3 * v3.x; accy += w3 * v3.y;
    }
    float2 r;
    r.x = accx * (1.0f / (float)K_NB);
    r.y = accy * (1.0f / (float)K_NB);
    out2[(size_t)m * (F_DIM / 2) + fp] = r;
}

extern "C" void kernel_launch(void* const* d_in, const int* in_sizes, int n_in,
                              void* d_out, int out_size, void* d_ws, size_t ws_size,
                              hipStream_t stream) {
    const float* features = (const float*)d_in[0];  // [N,64]
    const float* weights  = (const float*)d_in[1];  // [M,32,1]
    const int*   sel_idx  = (const int*)  d_in[2];  // [N,1]
    const int*   nidx     = (const int*)  d_in[3];  // [M,32]
    float*       out      = (float*)d_out;          // [M,64]

    const int N = in_sizes[2];            // 100000
    const int M = in_sizes[3] / K_NB;     // 100000

    size_t downh_bytes  = (size_t)M * F_DIM * sizeof(unsigned short); // 12.8 MB
    size_t cnt_bytes    = (size_t)M * sizeof(int);                    //  0.4 MB
    size_t bucket_bytes = (size_t)M * CAP * sizeof(int);              //  6.4 MB

    if (ws_size >= downh_bytes + cnt_bytes + bucket_bytes) {
        // Fast path: inverted-index build into a bf16 table, bf16 gather.
        unsigned short* down_h = (unsigned short*)d_ws;
        int* cnt    = (int*)((char*)d_ws + downh_bytes);
        int* bucket = cnt + M;

        hipMemsetAsync(cnt, 0, cnt_bytes, stream);
        bucket_fill_kernel<<<(N + 255) / 256, 256, 0, stream>>>(
            sel_idx, cnt, bucket, N);
        build_down_f_bf16_kernel<<<(M * 16 + 255) / 256, 256, 0, stream>>>(
            (const f32x4*)features, cnt, (const i32x4*)bucket, down_h, M);
        gather_mean_bf16_kernel<<<(M * 8 + 255) / 256, 256, 0, stream>>>(
            down_h, (const f32x4*)weights, (const i32x4*)nidx,
            (f32x4*)out, M);
    } else {
        // Fallback: fp32 table, atomic scatter, fp32 gather.
        float* down_f = (float*)d_ws;     // [M,64] = 25.6 MB
        hipMemsetAsync(down_f, 0, (size_t)M * F_DIM * sizeof(float), stream);
        scatter_add_kernel<<<(N * 32 + 255) / 256, 256, 0, stream>>>(
            features, sel_idx, down_f, N);
        gather_mean_f32_kernel<<<(M * 32 + 255) / 256, 256, 0, stream>>>(
            (const float2*)down_f, weights, nidx, (float2*)out, M);
    }
}